// Round 8
// baseline (129.401 us; speedup 1.0000x reference)
//
#include <hip/hip_runtime.h>

// logits = relu(T1[q] + sum_s T2[t_s]) @ W2^T + b2, vocab=64 so layer-1 is
// 9 table-row gathers from LDS-resident fp16 tables.
//
// R7 = R6 (split, 2048 x 2 iters, 8 blocks/CU) + async DMA staging:
//  - LDS staging switched to __builtin_amdgcn_global_load_lds width=16:
//    no VGPR round-trip, no explicit ds_write, loads stay in flight until
//    the single __syncthreads drain -> block prologue shortens by several
//    hundred cycles and overlaps with token loads + W2 fragment build.
//    (Staging layout is linear in tid: LDS dest = wave-uniform base +
//    lane*16, the DMA path's requirement.)
//  - Both iterations' token shfl broadcasts hoisted above the loop so
//    gather addresses are ready the moment the barrier clears.
//  - Everything else per R6/R4: per-lane dedup token loads issued first,
//    packed-token shfl, fp16 v_pk_add gather-accumulate, operand-swapped
//    MFMA (lane = element, regs = 4 consecutive logits), coalesced
//    nontemporal dwordx4 stores.

#define RSTRIDE_W 36                    // dwords per LDS row (32 data + 4 pad)
#define T2_OFF_W  (64 * RSTRIDE_W)      // 2304
#define LDS_DW    (2 * 64 * RSTRIDE_W)  // 4608 dwords = 18432 B

typedef __attribute__((ext_vector_type(4))) float    f32x4;
typedef __attribute__((ext_vector_type(4))) int      i32x4;
typedef __attribute__((ext_vector_type(8))) _Float16 f16x8;

// 32 blocks x 256 threads; job = (half, token) = blockIdx*4 + (tid>>6),
// thread j = output feature. T1 folds b1; T2 folds the 1/8 mean.
__global__ void prep_kernel(const float* __restrict__ embed,
                            const float* __restrict__ W1,
                            const float* __restrict__ b1,
                            unsigned short* __restrict__ T) {
  const int job  = blockIdx.x * 4 + (threadIdx.x >> 6);
  const int j    = threadIdx.x & 63;
  const int t    = job & 63;
  const int half = job >> 6;
  const f32x4* w4 = (const f32x4*)(W1 + j * 128 + half * 64);
  const f32x4* e4 = (const f32x4*)(embed + t * 64);
  float acc = 0.f;
#pragma unroll
  for (int k = 0; k < 16; ++k) {
    f32x4 a = w4[k], b = e4[k];
    acc += a[0] * b[0] + a[1] * b[1] + a[2] * b[2] + a[3] * b[3];
  }
  const float outv = half ? acc * 0.125f : acc + b1[j];
  ((_Float16*)T)[half * (64 * 2 * RSTRIDE_W) + t * (2 * RSTRIDE_W) + j] =
      (_Float16)outv;
}

// 2048 blocks x 256 threads; each wave: 2 iters x 16 elements (one MFMA
// tile each). Lane (qd=lane>>4, l15=lane&15) gathers features qd*8..+7
// (ks0) and 32+qd*8..+7 (ks1) of element b0+l15's 9 table rows as packed
// fp16, accumulates with v_pk_add_f16, ReLUs, then per n-tile
// mfma(W2frag, xfrag) -> lane's acc = 4 consecutive logits -> direct
// dwordx4 store.
__global__ __launch_bounds__(256, 4) void lru_kernel(
    const int*      __restrict__ seqs,
    const int*      __restrict__ qtok,
    const float*    __restrict__ W2,
    const float*    __restrict__ b2,
    const unsigned* __restrict__ T,
    float*          __restrict__ out) {
  __shared__ __align__(16) unsigned lds[LDS_DW];
  const int tid  = threadIdx.x;
  const int lane = tid & 63;
  const int wv   = tid >> 6;
  const int qd   = lane >> 4;
  const int l15  = lane & 15;

  // ---- token loads first: wave owns 32 elements, lane (&31) owns one ----
  const int wbase  = blockIdx.x * 128 + wv * 32;
  const int myelem = wbase + (lane & 31);
  const int* srow  = seqs + myelem * 24;
  const i32x4 t0 = __builtin_nontemporal_load((const i32x4*)(srow + 12));
  const i32x4 t1 = __builtin_nontemporal_load((const i32x4*)(srow + 16));
  const i32x4 t2 = __builtin_nontemporal_load((const i32x4*)(srow + 20));
  const int   tq = __builtin_nontemporal_load(qtok + myelem);

  // ---- async table staging: global -> LDS DMA, 16 B per lane ----
  // chunk layout is linear in tid (dest = wave-uniform base + lane*16);
  // loads drain at the __syncthreads below, overlapping all prologue work.
#pragma unroll
  for (int r = 0; r < 4; ++r) {
    const int c = tid + r * 256;           // uint4 chunk index
    __builtin_amdgcn_global_load_lds(
        (const __attribute__((address_space(1))) unsigned*)(T + c * 4),
        (__attribute__((address_space(3))) unsigned*)(lds + c * 4), 16, 0, 0);
  }
  if (tid < 128) {                         // tail: chunks 1024..1151
    const int c = 1024 + tid;
    __builtin_amdgcn_global_load_lds(
        (const __attribute__((address_space(1))) unsigned*)(T + c * 4),
        (__attribute__((address_space(3))) unsigned*)(lds + c * 4), 16, 0, 0);
  }

  // ---- W2 A-operand fragments (fp32 -> fp16) + bias vectors ----
  // lane supplies A[m = l15 -> logit nt*16+l15][k = ks*32 + qd*8 + i]
  f16x8 afW[4][2];
  f32x4 bb4[4];
#pragma unroll
  for (int nt = 0; nt < 4; ++nt) {
    const float* wr = W2 + (nt * 16 + l15) * 64 + qd * 8;
#pragma unroll
    for (int ks = 0; ks < 2; ++ks) {
      f32x4 w0 = *(const f32x4*)(wr + ks * 32);
      f32x4 w1 = *(const f32x4*)(wr + ks * 32 + 4);
      f16x8 f;
      f[0] = (_Float16)w0[0]; f[1] = (_Float16)w0[1];
      f[2] = (_Float16)w0[2]; f[3] = (_Float16)w0[3];
      f[4] = (_Float16)w1[0]; f[5] = (_Float16)w1[1];
      f[6] = (_Float16)w1[2]; f[7] = (_Float16)w1[3];
      afW[nt][ks] = f;
    }
    bb4[nt] = *(const f32x4*)(b2 + nt * 16 + qd * 4);
  }

  // pack this lane's 8 memory tokens into 2 dwords (values < 64), then
  // broadcast BOTH iterations' tokens before the barrier
  const int pk0 = t0.w | (t1.x << 8) | (t1.y << 16) | (t1.z << 24);
  const int pk1 = t1.w | (t2.x << 8) | (t2.y << 16) | (t2.z << 24);
  int u0[2], u1[2], qt[2];
#pragma unroll
  for (int it = 0; it < 2; ++it) {
    const int src = it * 16 + l15;
    u0[it] = __shfl(pk0, src);
    u1[it] = __shfl(pk1, src);
    qt[it] = __shfl(tq,  src);
  }
  __syncthreads();

#pragma unroll
  for (int it = 0; it < 2; ++it) {
    const int b0 = wbase + it * 16;

    // packed fp16 accumulators: a0 = features qd*8..+7, a1 = 32+qd*8..+7
    f16x8 a0, a1;
    {
      const f16x8* r1 = (const f16x8*)(lds + qt[it] * RSTRIDE_W + qd * 4);
      a0 = r1[0];          // dwords [qt*36+qd*4 .. +3]
      a1 = r1[4];          // +16 dwords (ks1 half)
    }
#pragma unroll
    for (int s = 0; s < 4; ++s) {
      const int tk = (u0[it] >> (8 * s)) & 63;
      const f16x8* r2 =
          (const f16x8*)(lds + T2_OFF_W + tk * RSTRIDE_W + qd * 4);
      a0 += r2[0];
      a1 += r2[4];
    }
#pragma unroll
    for (int s = 0; s < 4; ++s) {
      const int tk = (u1[it] >> (8 * s)) & 63;
      const f16x8* r2 =
          (const f16x8*)(lds + T2_OFF_W + tk * RSTRIDE_W + qd * 4);
      a0 += r2[0];
      a1 += r2[4];
    }
    const f16x8 z = {(_Float16)0, (_Float16)0, (_Float16)0, (_Float16)0,
                     (_Float16)0, (_Float16)0, (_Float16)0, (_Float16)0};
    const f16x8 afA = __builtin_elementwise_max(a0, z);
    const f16x8 afB = __builtin_elementwise_max(a1, z);

    // operand-swapped MFMA: lane = element b0+l15, regs = logits
    // nt*16 + qd*4 + r -> direct coalesced dwordx4 stores
    float* op = out + (size_t)(b0 + l15) * 64 + qd * 4;
#pragma unroll
    for (int nt = 0; nt < 4; ++nt) {
      f32x4 a = bb4[nt];
      a = __builtin_amdgcn_mfma_f32_16x16x32_f16(afW[nt][0], afA, a, 0, 0, 0);
      a = __builtin_amdgcn_mfma_f32_16x16x32_f16(afW[nt][1], afB, a, 0, 0, 0);
      __builtin_nontemporal_store(a, (f32x4*)(op + nt * 16));
    }
  }
}

extern "C" void kernel_launch(void* const* d_in, const int* in_sizes, int n_in,
                              void* d_out, int out_size, void* d_ws, size_t ws_size,
                              hipStream_t stream) {
  const int*   seqs  = (const int*)d_in[0];
  const int*   qtokp = (const int*)d_in[1];
  const float* embed = (const float*)d_in[2];
  const float* W1    = (const float*)d_in[3];
  const float* b1    = (const float*)d_in[4];
  const float* W2    = (const float*)d_in[5];
  const float* b2    = (const float*)d_in[6];
  float*       outp  = (float*)d_out;

  prep_kernel<<<dim3(32), dim3(256), 0, stream>>>(embed, W1, b1,
                                                  (unsigned short*)d_ws);
  lru_kernel<<<dim3(2048), dim3(256), 0, stream>>>(seqs, qtokp, W2, b2,
                                                   (const unsigned*)d_ws, outp);
}

// Round 9
// 118.009 us; speedup vs baseline: 1.0965x; 1.0965x over previous
//
#include <hip/hip_runtime.h>

// logits = relu(T1[q] + sum_s T2[t_s]) @ W2^T + b2, vocab=64 so layer-1 is
// 9 table-row gathers from LDS-resident fp16 tables.
//
// R9 = R8 minus ALL nontemporal hints (single-variable test).
//  - R8 counters: lru = 42.9 us, MfmaUtil 1.7%, VALUBusy 7.8%, write BW
//    1.78 TB/s (vs 6.3 achievable), WRITE_SIZE 76.5 MB for a 64 MB output
//    (1.2x amplification). Theory: nt stores bypass L2 -> 16x 64-B
//    segments per inst go to HBM as half-utilized 128-B bursts, and wave
//    progress couples to HBM write latency via streaming-write credits.
//    Normal stores let L2 assemble full lines (each wave-iter writes a
//    contiguous 4 KB) and drain at full write-back BW - which is exactly
//    how the harness's own 256 MiB fill sustains 6.3 TB/s.
//  - nt token loads likewise forbid L2 allocation; plain loads let
//    adjacent elements share seqs cache lines.
//  - Everything else identical to R8: split prep/lru, 2048 x 2 iters,
//    global_load_lds width-16 staging, hoisted packed-token shfl, fp16
//    v_pk_add gather-accumulate, operand-swapped MFMA, coalesced dwordx4
//    stores.

#define RSTRIDE_W 36                    // dwords per LDS row (32 data + 4 pad)
#define T2_OFF_W  (64 * RSTRIDE_W)      // 2304
#define LDS_DW    (2 * 64 * RSTRIDE_W)  // 4608 dwords = 18432 B

typedef __attribute__((ext_vector_type(4))) float    f32x4;
typedef __attribute__((ext_vector_type(4))) int      i32x4;
typedef __attribute__((ext_vector_type(8))) _Float16 f16x8;

// 32 blocks x 256 threads; job = (half, token) = blockIdx*4 + (tid>>6),
// thread j = output feature. T1 folds b1; T2 folds the 1/8 mean.
__global__ void prep_kernel(const float* __restrict__ embed,
                            const float* __restrict__ W1,
                            const float* __restrict__ b1,
                            unsigned short* __restrict__ T) {
  const int job  = blockIdx.x * 4 + (threadIdx.x >> 6);
  const int j    = threadIdx.x & 63;
  const int t    = job & 63;
  const int half = job >> 6;
  const f32x4* w4 = (const f32x4*)(W1 + j * 128 + half * 64);
  const f32x4* e4 = (const f32x4*)(embed + t * 64);
  float acc = 0.f;
#pragma unroll
  for (int k = 0; k < 16; ++k) {
    f32x4 a = w4[k], b = e4[k];
    acc += a[0] * b[0] + a[1] * b[1] + a[2] * b[2] + a[3] * b[3];
  }
  const float outv = half ? acc * 0.125f : acc + b1[j];
  ((_Float16*)T)[half * (64 * 2 * RSTRIDE_W) + t * (2 * RSTRIDE_W) + j] =
      (_Float16)outv;
}

// 2048 blocks x 256 threads; each wave: 2 iters x 16 elements (one MFMA
// tile each). Lane (qd=lane>>4, l15=lane&15) gathers features qd*8..+7
// (ks0) and 32+qd*8..+7 (ks1) of element b0+l15's 9 table rows as packed
// fp16, accumulates with v_pk_add_f16, ReLUs, then per n-tile
// mfma(W2frag, xfrag) -> lane's acc = 4 consecutive logits -> direct
// dwordx4 store.
__global__ __launch_bounds__(256, 4) void lru_kernel(
    const int*      __restrict__ seqs,
    const int*      __restrict__ qtok,
    const float*    __restrict__ W2,
    const float*    __restrict__ b2,
    const unsigned* __restrict__ T,
    float*          __restrict__ out) {
  __shared__ __align__(16) unsigned lds[LDS_DW];
  const int tid  = threadIdx.x;
  const int lane = tid & 63;
  const int wv   = tid >> 6;
  const int qd   = lane >> 4;
  const int l15  = lane & 15;

  // ---- token loads first: wave owns 32 elements, lane (&31) owns one ----
  const int wbase  = blockIdx.x * 128 + wv * 32;
  const int myelem = wbase + (lane & 31);
  const int* srow  = seqs + myelem * 24;
  const i32x4 t0 = *(const i32x4*)(srow + 12);
  const i32x4 t1 = *(const i32x4*)(srow + 16);
  const i32x4 t2 = *(const i32x4*)(srow + 20);
  const int   tq = qtok[myelem];

  // ---- async table staging: global -> LDS DMA, 16 B per lane ----
  // chunk layout is linear in tid (dest = wave-uniform base + lane*16);
  // loads drain at the __syncthreads below, overlapping all prologue work.
#pragma unroll
  for (int r = 0; r < 4; ++r) {
    const int c = tid + r * 256;           // uint4 chunk index
    __builtin_amdgcn_global_load_lds(
        (const __attribute__((address_space(1))) unsigned*)(T + c * 4),
        (__attribute__((address_space(3))) unsigned*)(lds + c * 4), 16, 0, 0);
  }
  if (tid < 128) {                         // tail: chunks 1024..1151
    const int c = 1024 + tid;
    __builtin_amdgcn_global_load_lds(
        (const __attribute__((address_space(1))) unsigned*)(T + c * 4),
        (__attribute__((address_space(3))) unsigned*)(lds + c * 4), 16, 0, 0);
  }

  // ---- W2 A-operand fragments (fp32 -> fp16) + bias vectors ----
  // lane supplies A[m = l15 -> logit nt*16+l15][k = ks*32 + qd*8 + i]
  f16x8 afW[4][2];
  f32x4 bb4[4];
#pragma unroll
  for (int nt = 0; nt < 4; ++nt) {
    const float* wr = W2 + (nt * 16 + l15) * 64 + qd * 8;
#pragma unroll
    for (int ks = 0; ks < 2; ++ks) {
      f32x4 w0 = *(const f32x4*)(wr + ks * 32);
      f32x4 w1 = *(const f32x4*)(wr + ks * 32 + 4);
      f16x8 f;
      f[0] = (_Float16)w0[0]; f[1] = (_Float16)w0[1];
      f[2] = (_Float16)w0[2]; f[3] = (_Float16)w0[3];
      f[4] = (_Float16)w1[0]; f[5] = (_Float16)w1[1];
      f[6] = (_Float16)w1[2]; f[7] = (_Float16)w1[3];
      afW[nt][ks] = f;
    }
    bb4[nt] = *(const f32x4*)(b2 + nt * 16 + qd * 4);
  }

  // pack this lane's 8 memory tokens into 2 dwords (values < 64), then
  // broadcast BOTH iterations' tokens before the barrier
  const int pk0 = t0.w | (t1.x << 8) | (t1.y << 16) | (t1.z << 24);
  const int pk1 = t1.w | (t2.x << 8) | (t2.y << 16) | (t2.z << 24);
  int u0[2], u1[2], qt[2];
#pragma unroll
  for (int it = 0; it < 2; ++it) {
    const int src = it * 16 + l15;
    u0[it] = __shfl(pk0, src);
    u1[it] = __shfl(pk1, src);
    qt[it] = __shfl(tq,  src);
  }
  __syncthreads();

#pragma unroll
  for (int it = 0; it < 2; ++it) {
    const int b0 = wbase + it * 16;

    // packed fp16 accumulators: a0 = features qd*8..+7, a1 = 32+qd*8..+7
    f16x8 a0, a1;
    {
      const f16x8* r1 = (const f16x8*)(lds + qt[it] * RSTRIDE_W + qd * 4);
      a0 = r1[0];          // dwords [qt*36+qd*4 .. +3]
      a1 = r1[4];          // +16 dwords (ks1 half)
    }
#pragma unroll
    for (int s = 0; s < 4; ++s) {
      const int tk = (u0[it] >> (8 * s)) & 63;
      const f16x8* r2 =
          (const f16x8*)(lds + T2_OFF_W + tk * RSTRIDE_W + qd * 4);
      a0 += r2[0];
      a1 += r2[4];
    }
#pragma unroll
    for (int s = 0; s < 4; ++s) {
      const int tk = (u1[it] >> (8 * s)) & 63;
      const f16x8* r2 =
          (const f16x8*)(lds + T2_OFF_W + tk * RSTRIDE_W + qd * 4);
      a0 += r2[0];
      a1 += r2[4];
    }
    const f16x8 z = {(_Float16)0, (_Float16)0, (_Float16)0, (_Float16)0,
                     (_Float16)0, (_Float16)0, (_Float16)0, (_Float16)0};
    const f16x8 afA = __builtin_elementwise_max(a0, z);
    const f16x8 afB = __builtin_elementwise_max(a1, z);

    // operand-swapped MFMA: lane = element b0+l15, regs = logits
    // nt*16 + qd*4 + r -> direct coalesced dwordx4 stores (via L2)
    float* op = out + (size_t)(b0 + l15) * 64 + qd * 4;
#pragma unroll
    for (int nt = 0; nt < 4; ++nt) {
      f32x4 a = bb4[nt];
      a = __builtin_amdgcn_mfma_f32_16x16x32_f16(afW[nt][0], afA, a, 0, 0, 0);
      a = __builtin_amdgcn_mfma_f32_16x16x32_f16(afW[nt][1], afB, a, 0, 0, 0);
      *(f32x4*)(op + nt * 16) = a;
    }
  }
}

extern "C" void kernel_launch(void* const* d_in, const int* in_sizes, int n_in,
                              void* d_out, int out_size, void* d_ws, size_t ws_size,
                              hipStream_t stream) {
  const int*   seqs  = (const int*)d_in[0];
  const int*   qtokp = (const int*)d_in[1];
  const float* embed = (const float*)d_in[2];
  const float* W1    = (const float*)d_in[3];
  const float* b1    = (const float*)d_in[4];
  const float* W2    = (const float*)d_in[5];
  const float* b2    = (const float*)d_in[6];
  float*       outp  = (float*)d_out;

  prep_kernel<<<dim3(32), dim3(256), 0, stream>>>(embed, W1, b1,
                                                  (unsigned short*)d_ws);
  lru_kernel<<<dim3(2048), dim3(256), 0, stream>>>(seqs, qtokp, W2, b2,
                                                   (const unsigned*)d_ws, outp);
}

// Round 12
// 110.753 us; speedup vs baseline: 1.1684x; 1.0655x over previous
//
#include <hip/hip_runtime.h>

// logits = relu(T1[q] + sum_s T2[t_s]) @ W2^T + b2, vocab=64 so layer-1 is
// 9 table-row gathers from LDS-resident fp16 tables.
//
// R10 (2nd resubmit - rounds 10 & 11 were container infra failures; this
// source never executed): consolidation of every A/B-validated component
// in the best geometry:
//  - 1024 blocks x 4 iters/wave (R2's best-measured geometry; half the
//    block prologues of the 2048-block variants, per-lane token dedup
//    covers all 4 iters exactly).
//  - global_load_lds width-16 DMA staging (R7): no VGPR round-trip, loads
//    in flight until the single __syncthreads, overlapping token loads +
//    W2 fragment build.
//  - operand-swapped MFMA (R3/R4): lane = element, regs = 4 consecutive
//    logits -> direct coalesced dwordx4 stores, no epilogue transpose.
//  - PLAIN cached loads/stores (R9's proven fix): nt stores capped write
//    drain at 1.78 TB/s (R8 counters: 42.9 us, WRITE_SIZE 76.5 MB for a
//    64 MB output); plain stores let L2 assemble full lines.
//  - hoisted packed-token shfl broadcast (3 shfls/iter).

#define RSTRIDE_W 36                    // dwords per LDS row (32 data + 4 pad)
#define T2_OFF_W  (64 * RSTRIDE_W)      // 2304
#define LDS_DW    (2 * 64 * RSTRIDE_W)  // 4608 dwords = 18432 B

typedef __attribute__((ext_vector_type(4))) float    f32x4;
typedef __attribute__((ext_vector_type(4))) int      i32x4;
typedef __attribute__((ext_vector_type(8))) _Float16 f16x8;

// 32 blocks x 256 threads; job = (half, token) = blockIdx*4 + (tid>>6),
// thread j = output feature. T1 folds b1; T2 folds the 1/8 mean.
__global__ void prep_kernel(const float* __restrict__ embed,
                            const float* __restrict__ W1,
                            const float* __restrict__ b1,
                            unsigned short* __restrict__ T) {
  const int job  = blockIdx.x * 4 + (threadIdx.x >> 6);
  const int j    = threadIdx.x & 63;
  const int t    = job & 63;
  const int half = job >> 6;
  const f32x4* w4 = (const f32x4*)(W1 + j * 128 + half * 64);
  const f32x4* e4 = (const f32x4*)(embed + t * 64);
  float acc = 0.f;
#pragma unroll
  for (int k = 0; k < 16; ++k) {
    f32x4 a = w4[k], b = e4[k];
    acc += a[0] * b[0] + a[1] * b[1] + a[2] * b[2] + a[3] * b[3];
  }
  const float outv = half ? acc * 0.125f : acc + b1[j];
  ((_Float16*)T)[half * (64 * 2 * RSTRIDE_W) + t * (2 * RSTRIDE_W) + j] =
      (_Float16)outv;
}

// 1024 blocks x 256 threads; each wave: 4 iters x 16 elements (one MFMA
// tile each). Lane (qd=lane>>4, l15=lane&15) gathers features qd*8..+7
// (ks0) and 32+qd*8..+7 (ks1) of element b0+l15's 9 table rows as packed
// fp16, accumulates with v_pk_add_f16, ReLUs, then per n-tile
// mfma(W2frag, xfrag) -> lane's acc = 4 consecutive logits -> direct
// dwordx4 store.
__global__ __launch_bounds__(256, 4) void lru_kernel(
    const int*      __restrict__ seqs,
    const int*      __restrict__ qtok,
    const float*    __restrict__ W2,
    const float*    __restrict__ b2,
    const unsigned* __restrict__ T,
    float*          __restrict__ out) {
  __shared__ __align__(16) unsigned lds[LDS_DW];
  const int tid  = threadIdx.x;
  const int lane = tid & 63;
  const int wv   = tid >> 6;
  const int qd   = lane >> 4;
  const int l15  = lane & 15;

  // ---- token loads first: wave owns 64 elements, lane owns one ----
  const int wbase  = blockIdx.x * 256 + wv * 64;
  const int myelem = wbase + lane;
  const int* srow  = seqs + myelem * 24;
  const i32x4 t0 = *(const i32x4*)(srow + 12);
  const i32x4 t1 = *(const i32x4*)(srow + 16);
  const i32x4 t2 = *(const i32x4*)(srow + 20);
  const int   tq = qtok[myelem];

  // ---- async table staging: global -> LDS DMA, 16 B per lane ----
  // chunk layout is linear in tid (dest = wave-uniform base + lane*16);
  // loads drain at the __syncthreads below, overlapping all prologue work.
#pragma unroll
  for (int r = 0; r < 4; ++r) {
    const int c = tid + r * 256;           // uint4 chunk index
    __builtin_amdgcn_global_load_lds(
        (const __attribute__((address_space(1))) unsigned*)(T + c * 4),
        (__attribute__((address_space(3))) unsigned*)(lds + c * 4), 16, 0, 0);
  }
  if (tid < 128) {                         // tail: chunks 1024..1151
    const int c = 1024 + tid;
    __builtin_amdgcn_global_load_lds(
        (const __attribute__((address_space(1))) unsigned*)(T + c * 4),
        (__attribute__((address_space(3))) unsigned*)(lds + c * 4), 16, 0, 0);
  }

  // ---- W2 A-operand fragments (fp32 -> fp16) + bias vectors ----
  // lane supplies A[m = l15 -> logit nt*16+l15][k = ks*32 + qd*8 + i]
  f16x8 afW[4][2];
  f32x4 bb4[4];
#pragma unroll
  for (int nt = 0; nt < 4; ++nt) {
    const float* wr = W2 + (nt * 16 + l15) * 64 + qd * 8;
#pragma unroll
    for (int ks = 0; ks < 2; ++ks) {
      f32x4 w0 = *(const f32x4*)(wr + ks * 32);
      f32x4 w1 = *(const f32x4*)(wr + ks * 32 + 4);
      f16x8 f;
      f[0] = (_Float16)w0[0]; f[1] = (_Float16)w0[1];
      f[2] = (_Float16)w0[2]; f[3] = (_Float16)w0[3];
      f[4] = (_Float16)w1[0]; f[5] = (_Float16)w1[1];
      f[6] = (_Float16)w1[2]; f[7] = (_Float16)w1[3];
      afW[nt][ks] = f;
    }
    bb4[nt] = *(const f32x4*)(b2 + nt * 16 + qd * 4);
  }

  // pack this lane's 8 memory tokens into 2 dwords (values < 64), then
  // broadcast ALL iterations' tokens before the barrier
  const int pk0 = t0.w | (t1.x << 8) | (t1.y << 16) | (t1.z << 24);
  const int pk1 = t1.w | (t2.x << 8) | (t2.y << 16) | (t2.z << 24);
  int u0[4], u1[4], qt[4];
#pragma unroll
  for (int it = 0; it < 4; ++it) {
    const int src = it * 16 + l15;
    u0[it] = __shfl(pk0, src);
    u1[it] = __shfl(pk1, src);
    qt[it] = __shfl(tq,  src);
  }
  __syncthreads();

#pragma unroll
  for (int it = 0; it < 4; ++it) {
    const int b0 = wbase + it * 16;

    // packed fp16 accumulators: a0 = features qd*8..+7, a1 = 32+qd*8..+7
    f16x8 a0, a1;
    {
      const f16x8* r1 = (const f16x8*)(lds + qt[it] * RSTRIDE_W + qd * 4);
      a0 = r1[0];          // dwords [qt*36+qd*4 .. +3]
      a1 = r1[4];          // +16 dwords (ks1 half)
    }
#pragma unroll
    for (int s = 0; s < 4; ++s) {
      const int tk = (u0[it] >> (8 * s)) & 63;
      const f16x8* r2 =
          (const f16x8*)(lds + T2_OFF_W + tk * RSTRIDE_W + qd * 4);
      a0 += r2[0];
      a1 += r2[4];
    }
#pragma unroll
    for (int s = 0; s < 4; ++s) {
      const int tk = (u1[it] >> (8 * s)) & 63;
      const f16x8* r2 =
          (const f16x8*)(lds + T2_OFF_W + tk * RSTRIDE_W + qd * 4);
      a0 += r2[0];
      a1 += r2[4];
    }
    const f16x8 z = {(_Float16)0, (_Float16)0, (_Float16)0, (_Float16)0,
                     (_Float16)0, (_Float16)0, (_Float16)0, (_Float16)0};
    const f16x8 afA = __builtin_elementwise_max(a0, z);
    const f16x8 afB = __builtin_elementwise_max(a1, z);

    // operand-swapped MFMA: lane = element b0+l15, regs = logits
    // nt*16 + qd*4 + r -> direct coalesced dwordx4 stores (via L2)
    float* op = out + (size_t)(b0 + l15) * 64 + qd * 4;
#pragma unroll
    for (int nt = 0; nt < 4; ++nt) {
      f32x4 a = bb4[nt];
      a = __builtin_amdgcn_mfma_f32_16x16x32_f16(afW[nt][0], afA, a, 0, 0, 0);
      a = __builtin_amdgcn_mfma_f32_16x16x32_f16(afW[nt][1], afB, a, 0, 0, 0);
      *(f32x4*)(op + nt * 16) = a;
    }
  }
}

extern "C" void kernel_launch(void* const* d_in, const int* in_sizes, int n_in,
                              void* d_out, int out_size, void* d_ws, size_t ws_size,
                              hipStream_t stream) {
  const int*   seqs  = (const int*)d_in[0];
  const int*   qtokp = (const int*)d_in[1];
  const float* embed = (const float*)d_in[2];
  const float* W1    = (const float*)d_in[3];
  const float* b1    = (const float*)d_in[4];
  const float* W2    = (const float*)d_in[5];
  const float* b2    = (const float*)d_in[6];
  float*       outp  = (float*)d_out;

  prep_kernel<<<dim3(32), dim3(256), 0, stream>>>(embed, W1, b1,
                                                  (unsigned short*)d_ws);
  lru_kernel<<<dim3(1024), dim3(256), 0, stream>>>(seqs, qtokp, W2, b2,
                                                   (const unsigned*)d_ws, outp);
}